// Round 1
// baseline (450.489 us; speedup 1.0000x reference)
//
#include <hip/hip_runtime.h>
#include <math.h>

// Problem constants (reference: B,H,N,D = 4,8,256,32)
constexpr int B = 4, H = 8, N = 256, D = 32;
constexpr int HD = H * D;  // 256

// One block per (b,h,i). 256 threads.
// Phase 1: stream edges_feats, write edge_out, reduce logits.
// Phase 2: softmax over j in LDS.
// Phase 3: out = attn @ v.
__global__ __launch_bounds__(256) void fused_edge_attn(
    const float* __restrict__ q,      // [B,H,N,D]
    const float* __restrict__ k,      // [B,H,N,D]
    const float* __restrict__ v,      // [B,H,N,D]
    const float* __restrict__ E,      // [B,H,N,N,D]
    const float* __restrict__ mask,   // [B,N,N]
    float* __restrict__ out,          // [B,N,H*D]
    float* __restrict__ edge_out)     // [B,N,N,H*D]  edge_out[b,j,i,h*D+d] = s[b,h,i,j,d]
{
    const int tid = threadIdx.x;
    const int blk = blockIdx.x;           // b*H*N + h*N + i
    const int i = blk % N;
    const int h = (blk / N) % H;
    const int b = blk / (N * H);

    __shared__ float logits[N];
    __shared__ float red[256];
    __shared__ float pbuf[N];

    const size_t bh = (size_t)(b * H + h);
    const float4* __restrict__ E4 = (const float4*)(E + (bh * N + (size_t)i) * (size_t)(N * D));
    const float4* __restrict__ K4 = (const float4*)(k + bh * (size_t)(N * D));
    const float*  qrow = q + (bh * N + (size_t)i) * D;

    // lane mapping for phase 1: tid = jq*8 + d4; d4 covers float4 index in D (8 of them)
    const int d4 = tid & 7;
    const int jq = tid >> 3;     // 0..31
    const float4 q4 = ((const float4*)qrow)[d4];

    #pragma unroll
    for (int iter = 0; iter < 8; ++iter) {
        const int j = iter * 32 + jq;
        const float4 e  = E4[j * 8 + d4];   // wave reads 1KiB contiguous
        const float4 kk = K4[j * 8 + d4];
        float4 s;
        s.x = q4.x * kk.x * e.x;
        s.y = q4.y * kk.y * e.y;
        s.z = q4.z * kk.z * e.z;
        s.w = q4.w * kk.w * e.w;
        // edge_out[b][j][i][h*D + d4*4 ...]: 8 lanes -> 128B contiguous segment
        const size_t eo_off = (((size_t)b * N + j) * N + i) * HD + h * D;
        ((float4*)(edge_out + eo_off))[d4] = s;
        // reduce 4 + 8-lane shuffle -> logit for (i,j)
        float partial = s.x + s.y + s.z + s.w;
        partial += __shfl_xor(partial, 1);
        partial += __shfl_xor(partial, 2);
        partial += __shfl_xor(partial, 4);
        if (d4 == 0) logits[j] = partial;   // each j written exactly once
    }
    __syncthreads();

    // ---- Phase 2: softmax over j = 0..255, thread tid owns j = tid ----
    const float scale = 0.17677669529663687f; // 1/sqrt(32)
    const float l = logits[tid] * scale + mask[((size_t)b * N + i) * N + tid];

    red[tid] = l;
    __syncthreads();
    #pragma unroll
    for (int s = 128; s > 0; s >>= 1) {
        if (tid < s) red[tid] = fmaxf(red[tid], red[tid + s]);
        __syncthreads();
    }
    const float m = red[0];
    __syncthreads();

    const float ex = __expf(l - m);
    red[tid] = ex;
    __syncthreads();
    #pragma unroll
    for (int s = 128; s > 0; s >>= 1) {
        if (tid < s) red[tid] += red[tid + s];
        __syncthreads();
    }
    const float denom = red[0];
    pbuf[tid] = ex / denom;
    __syncthreads();   // guards both pbuf visibility and red reuse below

    // ---- Phase 3: out[b,i,h*D+d] = sum_j p[j] * v[b,h,j,d] ----
    const float* vrow = v + bh * (size_t)(N * D);
    const int d = tid & 31;
    const int g = tid >> 5;   // 0..7
    float acc = 0.f;
    #pragma unroll
    for (int jj = 0; jj < 32; ++jj) {
        const int j = jj * 8 + g;           // block covers 1KiB contiguous of v per jj
        acc += pbuf[j] * vrow[j * D + d];
    }
    red[tid] = acc;
    __syncthreads();
    if (tid < 32) {
        float o = 0.f;
        #pragma unroll
        for (int g2 = 0; g2 < 8; ++g2) o += red[g2 * 32 + tid];
        out[(((size_t)b * N + i) * HD) + h * D + tid] = o;
    }
}

extern "C" void kernel_launch(void* const* d_in, const int* in_sizes, int n_in,
                              void* d_out, int out_size, void* d_ws, size_t ws_size,
                              hipStream_t stream) {
    const float* q    = (const float*)d_in[0];
    const float* k    = (const float*)d_in[1];
    const float* v    = (const float*)d_in[2];
    const float* E    = (const float*)d_in[3];
    const float* mask = (const float*)d_in[4];

    float* out      = (float*)d_out;                       // [B,N,H*D], first 262144 floats
    float* edge_out = out + (size_t)B * N * HD;            // [B,N,N,H*D]

    fused_edge_attn<<<B * H * N, 256, 0, stream>>>(q, k, v, E, mask, out, edge_out);
}

// Round 3
// 444.568 us; speedup vs baseline: 1.0133x; 1.0133x over previous
//
#include <hip/hip_runtime.h>
#include <math.h>

// Problem constants (reference: B,H,N,D = 4,8,256,32)
constexpr int B = 4, H = 8, N = 256, D = 32;
constexpr int HD = H * D;  // 256

// Native vector type for nontemporal builtins (HIP float4 is a struct and
// is rejected by __builtin_nontemporal_*).
typedef float nfloat4 __attribute__((ext_vector_type(4)));

// One block per (b,h,i). 256 threads.
// Phase 1: stream edges_feats (nontemporal), write edge_out (nontemporal),
//          wave-reduce logits.
// Phase 2: softmax over j via wave64 shuffle reductions (3 barriers total).
// Phase 3: out = attn @ v (v is L2-hot).
__global__ __launch_bounds__(256) void fused_edge_attn(
    const float* __restrict__ q,      // [B,H,N,D]
    const float* __restrict__ k,      // [B,H,N,D]
    const float* __restrict__ v,      // [B,H,N,D]
    const float* __restrict__ E,      // [B,H,N,N,D]
    const float* __restrict__ mask,   // [B,N,N]
    float* __restrict__ out,          // [B,N,H*D]
    float* __restrict__ edge_out)     // [B,N,N,H*D]  edge_out[b,j,i,h*D+d] = s[b,h,i,j,d]
{
    const int tid = threadIdx.x;
    const int blk = blockIdx.x;           // b*H*N + h*N + i
    const int i = blk % N;
    const int h = (blk / N) % H;
    const int b = blk / (N * H);

    __shared__ float logits[N];   // reused as pbuf after phase 2
    __shared__ float red[256];
    __shared__ float wred[4];
    __shared__ float wsum[4];

    const size_t bh = (size_t)(b * H + h);
    const nfloat4* __restrict__ E4 = (const nfloat4*)(E + (bh * N + (size_t)i) * (size_t)(N * D));
    const nfloat4* __restrict__ K4 = (const nfloat4*)(k + bh * (size_t)(N * D));
    const float*   qrow = q + (bh * N + (size_t)i) * D;

    // lane mapping for phase 1: tid = jq*8 + d4 (8 lanes span one j's 128B)
    const int d4 = tid & 7;
    const int jq = tid >> 3;     // 0..31
    const nfloat4 q4 = ((const nfloat4*)qrow)[d4];

    nfloat4* __restrict__ eo_base = (nfloat4*)(edge_out + ((size_t)b * N * N + i) * HD + h * D) + d4;

    #pragma unroll
    for (int iter = 0; iter < 8; ++iter) {
        const int j = iter * 32 + jq;
        const nfloat4 e  = __builtin_nontemporal_load(E4 + j * 8 + d4); // 1KiB contiguous per wave
        const nfloat4 kk = K4[j * 8 + d4];                              // L2-hot, keep cached
        const nfloat4 s = q4 * kk * e;
        // edge_out[b][j][i][h*D + d4*4 ...]: 8 lanes -> aligned 128B line
        __builtin_nontemporal_store(s, eo_base + (size_t)j * (N * HD / 4));
        // reduce 4 + 8-lane shuffle -> logit for (i,j)
        float partial = s.x + s.y + s.z + s.w;
        partial += __shfl_xor(partial, 1);
        partial += __shfl_xor(partial, 2);
        partial += __shfl_xor(partial, 4);
        if (d4 == 0) logits[j] = partial;   // each j written exactly once
    }
    __syncthreads();

    // ---- Phase 2: softmax over j = 0..255, thread tid owns j = tid ----
    const float scale = 0.17677669529663687f; // 1/sqrt(32)
    const float l = logits[tid] * scale + mask[((size_t)b * N + i) * N + tid];
    const int lane = tid & 63, wid = tid >> 6;

    float m = l;
    #pragma unroll
    for (int off = 32; off > 0; off >>= 1) m = fmaxf(m, __shfl_xor(m, off));
    if (lane == 0) wred[wid] = m;
    __syncthreads();
    m = fmaxf(fmaxf(wred[0], wred[1]), fmaxf(wred[2], wred[3]));

    const float ex = __expf(l - m);
    float ssum = ex;
    #pragma unroll
    for (int off = 32; off > 0; off >>= 1) ssum += __shfl_xor(ssum, off);
    if (lane == 0) wsum[wid] = ssum;
    __syncthreads();
    const float denom = wsum[0] + wsum[1] + wsum[2] + wsum[3];
    logits[tid] = ex / denom;           // logits[] now holds attention probs
    __syncthreads();

    // ---- Phase 3: out[b,i,h*D+d] = sum_j p[j] * v[b,h,j,d] ----
    const float* vrow = v + bh * (size_t)(N * D);
    const int d = tid & 31;
    const int g = tid >> 5;   // 0..7
    float acc = 0.f;
    #pragma unroll
    for (int jj = 0; jj < 32; ++jj) {
        const int j = jj * 8 + g;           // block covers 1KiB contiguous of v per jj
        acc += logits[j] * vrow[j * D + d];
    }
    red[tid] = acc;
    __syncthreads();
    if (tid < 32) {
        float o = red[tid] + red[32 + tid] + red[64 + tid] + red[96 + tid]
                + red[128 + tid] + red[160 + tid] + red[192 + tid] + red[224 + tid];
        out[(((size_t)b * N + i) * HD) + h * D + tid] = o;
    }
}

extern "C" void kernel_launch(void* const* d_in, const int* in_sizes, int n_in,
                              void* d_out, int out_size, void* d_ws, size_t ws_size,
                              hipStream_t stream) {
    const float* q    = (const float*)d_in[0];
    const float* k    = (const float*)d_in[1];
    const float* v    = (const float*)d_in[2];
    const float* E    = (const float*)d_in[3];
    const float* mask = (const float*)d_in[4];

    float* out      = (float*)d_out;                       // [B,N,H*D], first 262144 floats
    float* edge_out = out + (size_t)B * N * HD;            // [B,N,N,H*D]

    fused_edge_attn<<<B * H * N, 256, 0, stream>>>(q, k, v, E, mask, out, edge_out);
}